// Round 3
// baseline (469.916 us; speedup 1.0000x reference)
//
#include <hip/hip_runtime.h>
#include <cmath>

#define B_   64
#define LX_  1024
#define LY_  1024
#define D_   300
#define DP   320      // padded K / e dimension
#define DV   304      // padded d for PV (19 * 16)
#define BM   64       // s-tile rows per block (flash attn)
#define KV   32       // t-tile

using f32x4  = __attribute__((ext_vector_type(4))) float;
using bf16x8 = __attribute__((ext_vector_type(8))) __bf16;
using u32x4  = __attribute__((ext_vector_type(4))) unsigned int;
using u32x2  = __attribute__((ext_vector_type(2))) unsigned int;

static __device__ __forceinline__ unsigned short f2b(float f){
    unsigned u = __builtin_bit_cast(unsigned, f);
    u += 0x7FFFu + ((u >> 16) & 1u);          // round-to-nearest-even
    return (unsigned short)(u >> 16);
}

static __device__ __forceinline__ unsigned pk_bf16(float lo, float hi){
    unsigned r;
    asm volatile("v_cvt_pk_bf16_f32 %0, %1, %2" : "=v"(r) : "v"(lo), "v"(hi));
    return r;
}

static __device__ __forceinline__ bf16x8 ld_bf8(const unsigned short* p){
    u32x4 u = *(const u32x4*)p;
    return __builtin_bit_cast(bf16x8, u);
}

static __device__ __forceinline__ f32x4 mfma16(bf16x8 a, bf16x8 b, f32x4 c){
    return __builtin_amdgcn_mfma_f32_16x16x32_bf16(a, b, c, 0, 0, 0);
}

// ---------------- K0: W (300x300 f32) -> Wb (320x320 bf16, zero padded) ----
__global__ void k_wconv(const float* __restrict__ W, unsigned short* __restrict__ Wb){
    int i = blockIdx.x * 256 + threadIdx.x;
    if (i >= DP * DP) return;
    int e = i / DP, d = i % DP;
    float v = (e < D_ && d < D_) ? W[e * D_ + d] : 0.f;
    Wb[i] = f2b(v);
}

// ---------------- K2: y (b,t,d f32) -> yT (b,d,t bf16), d padded to 304 ----
__global__ __launch_bounds__(256) void k_ytrans(const float* __restrict__ Y,
                                                unsigned short* __restrict__ yT){
    __shared__ float tile[64][65];
    const int bid = blockIdx.x;           // 64 * 16 * 5
    const int b  = bid / 80;
    const int tt = (bid % 80) / 5;
    const int dt = bid % 5;
    const int t0 = tt * 64, d0 = dt * 64;
    const int tid = threadIdx.x;
    const int dl = tid & 63, qq = tid >> 6;
    #pragma unroll
    for (int r = 0; r < 16; ++r){
        const int tl = qq * 16 + r;
        const int d = d0 + dl;
        float v = (d < D_) ? Y[((long)b * LY_ + t0 + tl) * D_ + d] : 0.f;
        tile[tl][dl] = v;
    }
    __syncthreads();
    #pragma unroll
    for (int r = 0; r < 16; ++r){
        const int drow = d0 + qq * 16 + r;
        if (drow < DV){
            float v = (drow < D_) ? tile[dl][qq * 16 + r] : 0.f;
            yT[((long)b * DV + drow) * LY_ + t0 + dl] = f2b(v);
        }
    }
}

// ---------------- K1: proj = relu(Z @ W^T + b) for Z = concat(x,y) ---------
__global__ __launch_bounds__(256) void k_proj(const float* __restrict__ X,
        const float* __restrict__ Y, const float* __restrict__ bias,
        const unsigned short* __restrict__ Wb,
        unsigned short* __restrict__ Px, unsigned short* __restrict__ Py){
    const int tid = threadIdx.x;
    const int w = tid >> 6, l = tid & 63;
    const int lr = l & 15, lg = l >> 4;
    const long m0 = (long)blockIdx.x * 128;
    const bool isX = (m0 < (long)B_ * LX_);
    const float* S = isX ? X : Y;
    unsigned short* Dst = isX ? Px : Py;
    const long base = isX ? m0 : m0 - (long)B_ * LX_;

    u32x4 a[2][10];
    #pragma unroll
    for (int ms = 0; ms < 2; ++ms){
        const float* rp = S + (base + 32 * w + 16 * ms + lr) * D_;
        #pragma unroll
        for (int ks = 0; ks < 10; ++ks){
            const int k0 = ks * 32 + lg * 8;
            f32x4 v0 = {0,0,0,0}, v1 = {0,0,0,0};
            if (k0 + 4 <= D_) v0 = *(const f32x4*)(rp + k0);
            if (k0 + 8 <= D_) v1 = *(const f32x4*)(rp + k0 + 4);
            u32x4 u;
            u[0] = (unsigned)f2b(v0[0]) | ((unsigned)f2b(v0[1]) << 16);
            u[1] = (unsigned)f2b(v0[2]) | ((unsigned)f2b(v0[3]) << 16);
            u[2] = (unsigned)f2b(v1[0]) | ((unsigned)f2b(v1[1]) << 16);
            u[3] = (unsigned)f2b(v1[2]) | ((unsigned)f2b(v1[3]) << 16);
            a[ms][ks] = u;
        }
    }

    #pragma unroll 2
    for (int es = 0; es < 20; ++es){
        f32x4 acc0 = {0,0,0,0}, acc1 = {0,0,0,0};
        const unsigned short* wp = Wb + (es * 16 + lr) * DP + lg * 8;
        #pragma unroll
        for (int ks = 0; ks < 10; ++ks){
            bf16x8 bf = ld_bf8(wp + ks * 32);
            acc0 = mfma16(__builtin_bit_cast(bf16x8, a[0][ks]), bf, acc0);
            acc1 = mfma16(__builtin_bit_cast(bf16x8, a[1][ks]), bf, acc1);
        }
        const int e = es * 16 + lr;
        const float bv = (e < D_) ? bias[e] : 0.f;
        #pragma unroll
        for (int r = 0; r < 4; ++r){
            float v0 = acc0[r] + bv; v0 = v0 > 0.f ? v0 : 0.f;
            float v1 = acc1[r] + bv; v1 = v1 > 0.f ? v1 : 0.f;
            Dst[(base + 32 * w + lg * 4 + r) * DP + e]      = f2b(v0);
            Dst[(base + 32 * w + 16 + lg * 4 + r) * DP + e] = f2b(v1);
        }
    }
}

// ---------------- K3: flash attention (swapped-QK^T, in-register softmax) ---
// mask is int32 (harness converts bool -> int): 0 = keep, nonzero = masked out
__global__ __launch_bounds__(256, 3) void k_attn(const int* __restrict__ mask,
        const unsigned short* __restrict__ Px, const unsigned short* __restrict__ Py,
        const unsigned short* __restrict__ yT, float* __restrict__ out){
    __shared__ unsigned short Yp_lds[KV][328];   // 41 chunks/row (odd): conflict-free b128
    __shared__ unsigned short yT_lds[DV][40];    // 5 chunks/row (odd): conflict-free b128
    __shared__ unsigned short P_lds[BM][40];     // [s within block][t]

    const int tid = threadIdx.x;
    const int w = tid >> 6, l = tid & 63;
    const int lr = l & 15, lg = l >> 4;

    // XCD-bijective swizzle: all 16 s-blocks of a batch land on one XCD
    const int bid = blockIdx.x;              // 1024
    const int xcd = bid & 7;
    const int g = bid >> 3;
    const int b = xcd + 8 * (g >> 4);
    const int s0 = (g & 15) * BM;

    // Q fragments: wave w owns rows s0+16w .. s0+16w+15 (B-operand: col = lr)
    u32x4 q[10];
    {
        const unsigned short* qp = Px + ((long)b * LX_ + s0 + 16 * w + lr) * DP + lg * 8;
        #pragma unroll
        for (int ks = 0; ks < 10; ++ks) q[ks] = *(const u32x4*)(qp + ks * 32);
    }

    f32x4 acc[19];
    #pragma unroll
    for (int n = 0; n < 19; ++n) acc[n] = f32x4{0,0,0,0};
    float m_r = -INFINITY;    // running max for s-row = s0+16w+lr (scalar per lane)
    float l_r = 0.f;          // running denom for the same row

    const int* mrow = mask + (long)b * LY_;

    for (int t0 = 0; t0 < LY_; t0 += KV){
        // per-lane t coverage: t0 + 16*sub + 4*lg + r,  r = 0..3
        const int4 mv0 = *(const int4*)(mrow + t0 + lg * 4);
        const int4 mv1 = *(const int4*)(mrow + t0 + 16 + lg * 4);
        const int allm = (mv0.x && mv0.y && mv0.z && mv0.w &&
                          mv1.x && mv1.y && mv1.z && mv1.w) ? 1 : 0;
        if (__all(allm)) continue;     // tile fully masked (uniform across block)

        // stage Yp tile: 32 x 320 bf16
        #pragma unroll
        for (int j = 0; j < 5; ++j){
            const int id = tid + 256 * j;
            const int row = id / 40, c = id % 40;
            u32x4 v = *(const u32x4*)(Py + ((long)b * LY_ + t0 + row) * DP + c * 8);
            *(u32x4*)&Yp_lds[row][c * 8] = v;
        }
        // stage yT tile: 304 x 32 bf16
        #pragma unroll
        for (int j = 0; j < 5; ++j){
            const int id = tid + 256 * j;
            if (id < DV * 4){
                const int row = id >> 2, c = id & 3;
                u32x4 v = *(const u32x4*)(yT + ((long)b * DV + row) * LY_ + t0 + c * 8);
                *(u32x4*)&yT_lds[row][c * 8] = v;
            }
        }
        __syncthreads();

        // S^T = Yp @ Q^T : lane gets S[t0 + 16*sub + 4*lg + r][s = s0+16w+lr]
        f32x4 sv0 = {0,0,0,0}, sv1 = {0,0,0,0};
        #pragma unroll
        for (int ks = 0; ks < 10; ++ks){
            bf16x8 qf = __builtin_bit_cast(bf16x8, q[ks]);
            bf16x8 a0 = ld_bf8(&Yp_lds[lr][ks * 32 + lg * 8]);
            bf16x8 a1 = ld_bf8(&Yp_lds[16 + lr][ks * 32 + lg * 8]);
            sv0 = mfma16(a0, qf, sv0);
            sv1 = mfma16(a1, qf, sv1);
        }

        // masked scores (8 per lane, all for the same s-row)
        float v0[4], v1[4];
        v0[0] = sv0[0] + (mv0.x ? -3.0e38f : 0.f);
        v0[1] = sv0[1] + (mv0.y ? -3.0e38f : 0.f);
        v0[2] = sv0[2] + (mv0.z ? -3.0e38f : 0.f);
        v0[3] = sv0[3] + (mv0.w ? -3.0e38f : 0.f);
        v1[0] = sv1[0] + (mv1.x ? -3.0e38f : 0.f);
        v1[1] = sv1[1] + (mv1.y ? -3.0e38f : 0.f);
        v1[2] = sv1[2] + (mv1.z ? -3.0e38f : 0.f);
        v1[3] = sv1[3] + (mv1.w ? -3.0e38f : 0.f);

        // row max: 7 in-lane + 2 cross-lane (lanes lr, lr+16, lr+32, lr+48)
        float mx = fmaxf(fmaxf(fmaxf(v0[0], v0[1]), fmaxf(v0[2], v0[3])),
                         fmaxf(fmaxf(v1[0], v1[1]), fmaxf(v1[2], v1[3])));
        mx = fmaxf(mx, __shfl_xor(mx, 16));
        mx = fmaxf(mx, __shfl_xor(mx, 32));
        const float nm = fmaxf(m_r, mx);

        float p0[4], p1[4];
        float ps = 0.f;
        #pragma unroll
        for (int r = 0; r < 4; ++r){
            p0[r] = __expf(v0[r] - nm);
            p1[r] = __expf(v1[r] - nm);
            ps += p0[r] + p1[r];
        }
        ps += __shfl_xor(ps, 16);
        ps += __shfl_xor(ps, 32);
        const float sc = __expf(m_r - nm);   // first tile: exp(-inf)=0
        l_r = l_r * sc + ps;
        m_r = nm;

        // rescale acc: acc rows live at s = 4*lg + r -> broadcast sc from lane (4*lg+r)
        float scr[4];
        #pragma unroll
        for (int r = 0; r < 4; ++r) scr[r] = __shfl(sc, lg * 4 + r);
        #pragma unroll
        for (int n = 0; n < 19; ++n){
            #pragma unroll
            for (int r = 0; r < 4; ++r) acc[n][r] *= scr[r];
        }

        // pack P to bf16 in-register, write own wave's rows (no barrier needed)
        const unsigned c00 = pk_bf16(p0[0], p0[1]);
        const unsigned c01 = pk_bf16(p0[2], p0[3]);
        const unsigned c10 = pk_bf16(p1[0], p1[1]);
        const unsigned c11 = pk_bf16(p1[2], p1[3]);
        *(u32x2*)&P_lds[16 * w + lr][4 * lg]      = u32x2{c00, c01};
        *(u32x2*)&P_lds[16 * w + lr][16 + 4 * lg] = u32x2{c10, c11};

        // O += P @ y : K = 32 (one MFMA step), 19 d-subtiles
        bf16x8 pf = ld_bf8(&P_lds[16 * w + lr][lg * 8]);
        #pragma unroll
        for (int n = 0; n < 19; ++n){
            bf16x8 vf = ld_bf8(&yT_lds[n * 16 + lr][lg * 8]);
            acc[n] = mfma16(pf, vf, acc[n]);
        }
        __syncthreads();   // before next iteration's staging overwrites
    }

    // normalize: 1/l for rows s = 4*lg + r via broadcast
    const float il = 1.f / l_r;
    float invr[4];
    #pragma unroll
    for (int r = 0; r < 4; ++r) invr[r] = __shfl(il, lg * 4 + r);

    #pragma unroll
    for (int n = 0; n < 19; ++n){
        const int d = n * 16 + lr;
        if (d < D_){
            #pragma unroll
            for (int r = 0; r < 4; ++r){
                out[((long)b * LX_ + s0 + 16 * w + lg * 4 + r) * D_ + d] = acc[n][r] * invr[r];
            }
        }
    }
}

extern "C" void kernel_launch(void* const* d_in, const int* in_sizes, int n_in,
                              void* d_out, int out_size, void* d_ws, size_t ws_size,
                              hipStream_t stream){
    const float* x = (const float*)d_in[0];
    const float* y = (const float*)d_in[1];
    const int* ymask = (const int*)d_in[2];
    const float* W = (const float*)d_in[3];
    const float* bias = (const float*)d_in[4];
    float* out = (float*)d_out;

    unsigned short* Wb  = (unsigned short*)d_ws;
    unsigned short* Px  = (unsigned short*)((char*)d_ws + (1 << 18));
    unsigned short* Py  = (unsigned short*)((char*)d_ws + (1 << 18) + 41943040LL);
    unsigned short* yTw = (unsigned short*)((char*)d_ws + (1 << 18) + 83886080LL);

    hipLaunchKernelGGL(k_wconv, dim3((DP * DP + 255) / 256), dim3(256), 0, stream, W, Wb);
    hipLaunchKernelGGL(k_proj,  dim3(1024), dim3(256), 0, stream, x, y, bias, Wb, Px, Py);
    hipLaunchKernelGGL(k_ytrans, dim3(64 * 80), dim3(256), 0, stream, y, yTw);
    hipLaunchKernelGGL(k_attn,  dim3(1024), dim3(256), 0, stream, ymask, Px, Py, yTw, out);
}

// Round 4
// 310.138 us; speedup vs baseline: 1.5152x; 1.5152x over previous
//
#include <hip/hip_runtime.h>
#include <cmath>

#define B_   64
#define LX_  1024
#define LY_  1024
#define D_   300
#define DP   320      // padded K / e dimension
#define DV   304      // padded d for PV (19 * 16)
#define BM   64       // s-tile rows per block (flash attn)
#define KV   32       // t-tile
#define NT   (LY_ / KV)

using f32x4  = __attribute__((ext_vector_type(4))) float;
using bf16x8 = __attribute__((ext_vector_type(8))) __bf16;
using u32x4  = __attribute__((ext_vector_type(4))) unsigned int;
using u32x2  = __attribute__((ext_vector_type(2))) unsigned int;

static __device__ __forceinline__ unsigned short f2b(float f){
    unsigned u = __builtin_bit_cast(unsigned, f);
    u += 0x7FFFu + ((u >> 16) & 1u);          // round-to-nearest-even
    return (unsigned short)(u >> 16);
}

static __device__ __forceinline__ unsigned pk_bf16(float lo, float hi){
    unsigned r;
    asm volatile("v_cvt_pk_bf16_f32 %0, %1, %2" : "=v"(r) : "v"(lo), "v"(hi));
    return r;
}

static __device__ __forceinline__ bf16x8 ld_bf8(const unsigned short* p){
    u32x4 u = *(const u32x4*)p;
    return __builtin_bit_cast(bf16x8, u);
}

static __device__ __forceinline__ f32x4 mfma16(bf16x8 a, bf16x8 b, f32x4 c){
    return __builtin_amdgcn_mfma_f32_16x16x32_bf16(a, b, c, 0, 0, 0);
}

// ---------------- K0: W (300x300 f32) -> Wb (320x320 bf16, zero padded) ----
__global__ void k_wconv(const float* __restrict__ W, unsigned short* __restrict__ Wb){
    int i = blockIdx.x * 256 + threadIdx.x;
    if (i >= DP * DP) return;
    int e = i / DP, d = i % DP;
    float v = (e < D_ && d < D_) ? W[e * D_ + d] : 0.f;
    Wb[i] = f2b(v);
}

// ---------------- K2: y (b,t,d f32) -> yT (b,d,t bf16), d padded to 304 ----
__global__ __launch_bounds__(256) void k_ytrans(const float* __restrict__ Y,
                                                unsigned short* __restrict__ yT){
    __shared__ float tile[64][65];
    const int bid = blockIdx.x;           // 64 * 16 * 5
    const int b  = bid / 80;
    const int tt = (bid % 80) / 5;
    const int dt = bid % 5;
    const int t0 = tt * 64, d0 = dt * 64;
    const int tid = threadIdx.x;
    const int dl = tid & 63, qq = tid >> 6;
    #pragma unroll
    for (int r = 0; r < 16; ++r){
        const int tl = qq * 16 + r;
        const int d = d0 + dl;
        float v = (d < D_) ? Y[((long)b * LY_ + t0 + tl) * D_ + d] : 0.f;
        tile[tl][dl] = v;
    }
    __syncthreads();
    #pragma unroll
    for (int r = 0; r < 16; ++r){
        const int drow = d0 + qq * 16 + r;
        if (drow < DV){
            float v = (drow < D_) ? tile[dl][qq * 16 + r] : 0.f;
            yT[((long)b * DV + drow) * LY_ + t0 + dl] = f2b(v);
        }
    }
}

// ---------------- K1: proj = relu(Z @ W^T + b) for Z = concat(x,y) ---------
__global__ __launch_bounds__(256) void k_proj(const float* __restrict__ X,
        const float* __restrict__ Y, const float* __restrict__ bias,
        const unsigned short* __restrict__ Wb,
        unsigned short* __restrict__ Px, unsigned short* __restrict__ Py){
    const int tid = threadIdx.x;
    const int w = tid >> 6, l = tid & 63;
    const int lr = l & 15, lg = l >> 4;
    const long m0 = (long)blockIdx.x * 128;
    const bool isX = (m0 < (long)B_ * LX_);
    const float* S = isX ? X : Y;
    unsigned short* Dst = isX ? Px : Py;
    const long base = isX ? m0 : m0 - (long)B_ * LX_;

    u32x4 a[2][10];
    #pragma unroll
    for (int ms = 0; ms < 2; ++ms){
        const float* rp = S + (base + 32 * w + 16 * ms + lr) * D_;
        #pragma unroll
        for (int ks = 0; ks < 10; ++ks){
            const int k0 = ks * 32 + lg * 8;
            f32x4 v0 = {0,0,0,0}, v1 = {0,0,0,0};
            if (k0 + 4 <= D_) v0 = *(const f32x4*)(rp + k0);
            if (k0 + 8 <= D_) v1 = *(const f32x4*)(rp + k0 + 4);
            u32x4 u;
            u[0] = (unsigned)f2b(v0[0]) | ((unsigned)f2b(v0[1]) << 16);
            u[1] = (unsigned)f2b(v0[2]) | ((unsigned)f2b(v0[3]) << 16);
            u[2] = (unsigned)f2b(v1[0]) | ((unsigned)f2b(v1[1]) << 16);
            u[3] = (unsigned)f2b(v1[2]) | ((unsigned)f2b(v1[3]) << 16);
            a[ms][ks] = u;
        }
    }

    #pragma unroll 2
    for (int es = 0; es < 20; ++es){
        f32x4 acc0 = {0,0,0,0}, acc1 = {0,0,0,0};
        const unsigned short* wp = Wb + (es * 16 + lr) * DP + lg * 8;
        #pragma unroll
        for (int ks = 0; ks < 10; ++ks){
            bf16x8 bf = ld_bf8(wp + ks * 32);
            acc0 = mfma16(__builtin_bit_cast(bf16x8, a[0][ks]), bf, acc0);
            acc1 = mfma16(__builtin_bit_cast(bf16x8, a[1][ks]), bf, acc1);
        }
        const int e = es * 16 + lr;
        const float bv = (e < D_) ? bias[e] : 0.f;
        #pragma unroll
        for (int r = 0; r < 4; ++r){
            float v0 = acc0[r] + bv; v0 = v0 > 0.f ? v0 : 0.f;
            float v1 = acc1[r] + bv; v1 = v1 > 0.f ? v1 : 0.f;
            Dst[(base + 32 * w + lg * 4 + r) * DP + e]      = f2b(v0);
            Dst[(base + 32 * w + 16 + lg * 4 + r) * DP + e] = f2b(v1);
        }
    }
}

// ---------------- K3: flash attention (swapped-QK^T + async-stage split) ----
// mask is int32: 0 = keep, nonzero = masked out
__global__ __launch_bounds__(256, 2) void k_attn(const int* __restrict__ mask,
        const unsigned short* __restrict__ Px, const unsigned short* __restrict__ Py,
        const unsigned short* __restrict__ yT, float* __restrict__ out){
    __shared__ unsigned short Yp_lds[KV][328];   // odd chunk-stride: conflict-light b128
    __shared__ unsigned short yT_lds[DV][40];
    __shared__ unsigned short P_lds[BM][40];     // [s within block][t]

    const int tid = threadIdx.x;
    const int w = tid >> 6, l = tid & 63;
    const int lr = l & 15, lg = l >> 4;

    // XCD-bijective swizzle: all 16 s-blocks of a batch land on one XCD
    const int bid = blockIdx.x;              // 1024
    const int xcd = bid & 7;
    const int g = bid >> 3;
    const int b = xcd + 8 * (g >> 4);
    const int s0 = (g & 15) * BM;

    // Q fragments: wave w owns rows s0+16w .. s0+16w+15 (B-operand: col = lr)
    u32x4 q[10];
    {
        const unsigned short* qp = Px + ((long)b * LX_ + s0 + 16 * w + lr) * DP + lg * 8;
        #pragma unroll
        for (int ks = 0; ks < 10; ++ks) q[ks] = *(const u32x4*)(qp + ks * 32);
    }

    // ---- staging address setup (per thread, loop-invariant row/col) ----
    const unsigned short* srcYp[5];
    unsigned short*       dstYp[5];
    #pragma unroll
    for (int j = 0; j < 5; ++j){
        const int id = tid + 256 * j;            // 0..1279
        const int row = id / 40, c = id % 40;    // chunk of 8 u16
        srcYp[j] = Py + ((long)b * LY_ + row) * DP + c * 8;
        dstYp[j] = &Yp_lds[row][c * 8];
    }
    const unsigned short* srcYT[5];
    unsigned short*       dstYT[5];
    #pragma unroll
    for (int j = 0; j < 5; ++j){
        const int id = tid + 256 * j;            // valid if < 1216
        const int row = (id >> 2) < DV ? (id >> 2) : (DV - 1);
        const int c = id & 3;
        srcYT[j] = yT + ((long)b * DV + row) * LY_ + c * 8;
        dstYT[j] = &yT_lds[row][c * 8];
    }
    const bool v4 = (tid < 192);                 // j=4 validity for yT chunks

    const int* mrow = mask + (long)b * LY_;

    // ---- prologue: stage tile 0 ----
    u32x4 pA[5], pT[5];
    #pragma unroll
    for (int j = 0; j < 5; ++j) pA[j] = *(const u32x4*)srcYp[j];
    #pragma unroll
    for (int j = 0; j < 4; ++j) pT[j] = *(const u32x4*)srcYT[j];
    if (v4) pT[4] = *(const u32x4*)srcYT[4];
    int4 m0v = *(const int4*)(mrow + lg * 4);
    int4 m1v = *(const int4*)(mrow + 16 + lg * 4);
    #pragma unroll
    for (int j = 0; j < 5; ++j) *(u32x4*)dstYp[j] = pA[j];
    #pragma unroll
    for (int j = 0; j < 4; ++j) *(u32x4*)dstYT[j] = pT[j];
    if (v4) *(u32x4*)dstYT[4] = pT[4];
    __syncthreads();

    f32x4 acc[19];
    #pragma unroll
    for (int n = 0; n < 19; ++n) acc[n] = f32x4{0,0,0,0};
    float m_r = -INFINITY;    // running max for s-row = s0+16w+lr
    float l_r = 0.f;

    for (int it = 0; it < NT; ++it){
        const bool notlast = (it < NT - 1);

        // ---- A: issue next tile's global loads (consumed after barrier) ----
        int4 mn0, mn1;
        if (notlast){
            #pragma unroll
            for (int j = 0; j < 5; ++j){ srcYp[j] += KV * DP; pA[j] = *(const u32x4*)srcYp[j]; }
            #pragma unroll
            for (int j = 0; j < 4; ++j){ srcYT[j] += KV;      pT[j] = *(const u32x4*)srcYT[j]; }
            srcYT[4] += KV;
            if (v4) pT[4] = *(const u32x4*)srcYT[4];
            mn0 = *(const int4*)(mrow + (it + 1) * KV + lg * 4);
            mn1 = *(const int4*)(mrow + (it + 1) * KV + 16 + lg * 4);
        }

        // ---- B: compute on current tile (skip if fully masked) ----
        const int allm = (m0v.x && m0v.y && m0v.z && m0v.w &&
                          m1v.x && m1v.y && m1v.z && m1v.w) ? 1 : 0;
        if (!__all(allm)){
            // S^T = Yp @ Q^T : lane holds S[t = it*KV + 16*sub + 4*lg + r][s = s0+16w+lr]
            f32x4 sv0 = {0,0,0,0}, sv1 = {0,0,0,0};
            #pragma unroll
            for (int ks = 0; ks < 10; ++ks){
                bf16x8 qf = __builtin_bit_cast(bf16x8, q[ks]);
                bf16x8 a0 = ld_bf8(&Yp_lds[lr][ks * 32 + lg * 8]);
                bf16x8 a1 = ld_bf8(&Yp_lds[16 + lr][ks * 32 + lg * 8]);
                sv0 = mfma16(a0, qf, sv0);
                sv1 = mfma16(a1, qf, sv1);
            }

            float v0[4], v1[4];
            v0[0] = sv0[0] + (m0v.x ? -3.0e38f : 0.f);
            v0[1] = sv0[1] + (m0v.y ? -3.0e38f : 0.f);
            v0[2] = sv0[2] + (m0v.z ? -3.0e38f : 0.f);
            v0[3] = sv0[3] + (m0v.w ? -3.0e38f : 0.f);
            v1[0] = sv1[0] + (m1v.x ? -3.0e38f : 0.f);
            v1[1] = sv1[1] + (m1v.y ? -3.0e38f : 0.f);
            v1[2] = sv1[2] + (m1v.z ? -3.0e38f : 0.f);
            v1[3] = sv1[3] + (m1v.w ? -3.0e38f : 0.f);

            float mx = fmaxf(fmaxf(fmaxf(v0[0], v0[1]), fmaxf(v0[2], v0[3])),
                             fmaxf(fmaxf(v1[0], v1[1]), fmaxf(v1[2], v1[3])));
            mx = fmaxf(mx, __shfl_xor(mx, 16));
            mx = fmaxf(mx, __shfl_xor(mx, 32));
            const float nm = fmaxf(m_r, mx);

            float p0[4], p1[4];
            float ps = 0.f;
            #pragma unroll
            for (int r = 0; r < 4; ++r){
                p0[r] = __expf(v0[r] - nm);
                p1[r] = __expf(v1[r] - nm);
                ps += p0[r] + p1[r];
            }
            ps += __shfl_xor(ps, 16);
            ps += __shfl_xor(ps, 32);
            const float sc = __expf(m_r - nm);   // first tile: exp(-inf)=0
            l_r = l_r * sc + ps;
            m_r = nm;

            // rescale acc rows (s = 4*lg + r): broadcast sc from lane 4*lg+r
            float scr[4];
            #pragma unroll
            for (int r = 0; r < 4; ++r) scr[r] = __shfl(sc, lg * 4 + r);
            #pragma unroll
            for (int n = 0; n < 19; ++n){
                #pragma unroll
                for (int r = 0; r < 4; ++r) acc[n][r] *= scr[r];
            }

            // pack P -> bf16, write own wave's rows (within-wave dependency only)
            const unsigned c00 = pk_bf16(p0[0], p0[1]);
            const unsigned c01 = pk_bf16(p0[2], p0[3]);
            const unsigned c10 = pk_bf16(p1[0], p1[1]);
            const unsigned c11 = pk_bf16(p1[2], p1[3]);
            *(u32x2*)&P_lds[16 * w + lr][4 * lg]      = u32x2{c00, c01};
            *(u32x2*)&P_lds[16 * w + lr][16 + 4 * lg] = u32x2{c10, c11};

            // O += P @ y
            bf16x8 pf = ld_bf8(&P_lds[16 * w + lr][lg * 8]);
            #pragma unroll
            for (int n = 0; n < 19; ++n){
                bf16x8 vf = ld_bf8(&yT_lds[n * 16 + lr][lg * 8]);
                acc[n] = mfma16(pf, vf, acc[n]);
            }
        }

        __syncthreads();           // all waves done reading LDS (drains prefetch vmcnt)
        if (notlast){
            #pragma unroll
            for (int j = 0; j < 5; ++j) *(u32x4*)dstYp[j] = pA[j];
            #pragma unroll
            for (int j = 0; j < 4; ++j) *(u32x4*)dstYT[j] = pT[j];
            if (v4) *(u32x4*)dstYT[4] = pT[4];
            m0v = mn0; m1v = mn1;
        }
        __syncthreads();           // LDS ready for next iteration
    }

    // normalize: 1/l for rows s = 4*lg + r via broadcast
    const float il = 1.f / l_r;
    float invr[4];
    #pragma unroll
    for (int r = 0; r < 4; ++r) invr[r] = __shfl(il, lg * 4 + r);

    #pragma unroll
    for (int n = 0; n < 19; ++n){
        const int d = n * 16 + lr;
        if (d < D_){
            #pragma unroll
            for (int r = 0; r < 4; ++r){
                out[((long)b * LX_ + s0 + 16 * w + lg * 4 + r) * D_ + d] = acc[n][r] * invr[r];
            }
        }
    }
}

extern "C" void kernel_launch(void* const* d_in, const int* in_sizes, int n_in,
                              void* d_out, int out_size, void* d_ws, size_t ws_size,
                              hipStream_t stream){
    const float* x = (const float*)d_in[0];
    const float* y = (const float*)d_in[1];
    const int* ymask = (const int*)d_in[2];
    const float* W = (const float*)d_in[3];
    const float* bias = (const float*)d_in[4];
    float* out = (float*)d_out;

    unsigned short* Wb  = (unsigned short*)d_ws;
    unsigned short* Px  = (unsigned short*)((char*)d_ws + (1 << 18));
    unsigned short* Py  = (unsigned short*)((char*)d_ws + (1 << 18) + 41943040LL);
    unsigned short* yTw = (unsigned short*)((char*)d_ws + (1 << 18) + 83886080LL);

    hipLaunchKernelGGL(k_wconv, dim3((DP * DP + 255) / 256), dim3(256), 0, stream, W, Wb);
    hipLaunchKernelGGL(k_proj,  dim3(1024), dim3(256), 0, stream, x, y, bias, Wb, Px, Py);
    hipLaunchKernelGGL(k_ytrans, dim3(64 * 80), dim3(256), 0, stream, y, yTw);
    hipLaunchKernelGGL(k_attn,  dim3(1024), dim3(256), 0, stream, ymask, Px, Py, yTw, out);
}